// Round 6
// baseline (164.216 us; speedup 1.0000x reference)
//
#include <hip/hip_runtime.h>

#define G_ 100
#define T_ 24
#define TILE (G_ * T_)            // 2400 floats per (b,pass) tile
#define BPB 8                     // b's per block (both passes in-block)
#define BLOCK (BPB * 2 * T_)      // 384 threads = 6 waves; 192 %% 64 == 0
                                  // -> every wave is pass-uniform

typedef float vfloat4 __attribute__((ext_vector_type(4)));

// Merit-order chunk, full-lane: every lane owns one (b,pass,t) column.
// N row loads issued in one flight (64 lanes x 4B = 256B payload/inst,
// 3-4 coalesced segments spanning the wave's ~2.7 tiles), then the serial
// clip-scan, allocs stored directly (write-once kernel-wide: no fences).
// ord/bg come from per-wave registers via v_readlane (uniform -> SGPR).
template<int N>
__device__ __forceinline__ void scan_chunk(int k0,
    const float* __restrict__ capp,          // R_p[b] + t (per-lane)
    float* __restrict__ gcol,                // out tile + t (per-lane)
    int ord_lo, int ord_hi, float bg_lo, float bg_hi, float ratio,
    float dem, float& before, float& objp)
{
    int gg[N]; float pr[N], cap[N];
#pragma unroll
    for (int j = 0; j < N; ++j) {
        const int idx = k0 + j;              // compile-time constant
        if (idx < 64) {
            gg[j] = __builtin_amdgcn_readlane(ord_lo, idx);
            pr[j] = ratio * __int_as_float(
                        __builtin_amdgcn_readlane(__float_as_int(bg_lo), idx));
        } else {
            gg[j] = __builtin_amdgcn_readlane(ord_hi, idx - 64);
            pr[j] = ratio * __int_as_float(
                        __builtin_amdgcn_readlane(__float_as_int(bg_hi), idx - 64));
        }
    }
#pragma unroll
    for (int j = 0; j < N; ++j) cap[j] = capp[gg[j] * T_];   // N loads in flight
#pragma unroll
    for (int j = 0; j < N; ++j) {
        float a = fminf(fmaxf(dem - before, 0.f), cap[j]);
        before += cap[j];
        objp = fmaf(pr[j], a, objp);
        gcol[gg[j] * T_] = a;                // single write, own row
    }
}

__global__ __launch_bounds__(BLOCK, 8) void dispatch_kernel(
    const float* __restrict__ R_up, const float* __restrict__ R_dn,
    const float* __restrict__ omega,
    const float* __restrict__ b_G, const float* __restrict__ voll,
    const float* __restrict__ vosp, const float* __restrict__ ru,
    const float* __restrict__ rd,
    float* __restrict__ out, int B)
{
    __shared__ float s_bgraw[G_];
    __shared__ int   s_ord[128];
    __shared__ float s_bgs[128];
    __shared__ float s_oc[BLOCK];

    const int tid = threadIdx.x;

    // ---- ONE sort serves both passes: c_up = 1.5*b_G, c_dn = 1.2*b_G are
    // positive scalings -> argsort (incl. stable ties) is identical; slack
    // (voll=1000 / vosp=500) strictly exceeds every gen price (<=75) so it
    // is always rank 100. Stable rank-sort of b_G == jnp.argsort semantics.
    if (tid < G_) s_bgraw[tid] = b_G[tid];
    if (tid >= G_ && tid < 128) { s_ord[tid] = 0; s_bgs[tid] = 0.f; }
    __syncthreads();
    if (tid < G_) {
        const float m = s_bgraw[tid];
        int r = 0;
        for (int j = 0; j < G_; ++j) {
            const float v = s_bgraw[j];
            r += (v < m) || (v == m && j < tid);
        }
        s_ord[r] = tid;  s_bgs[r] = m;
    }
    __syncthreads();

    // ---- column decode: lane owns one (b, pass, t) column ----
    const int lane = tid & 63;
    const int pi = tid / (BPB * T_);          // wave-uniform (192 % 64 == 0)
    const int rm = tid % (BPB * T_);
    const int b  = blockIdx.x * BPB + rm / T_;
    const int t  = rm % T_;
    const size_t bgt = (size_t)B * TILE;

    // cache sorted merit order in per-wave registers (readlane source)
    const int hi_ok = (lane < G_ - 64);       // ranks 64..99 live in lanes 0..35
    const int   ord_lo = s_ord[lane];
    const int   ord_hi = hi_ok ? s_ord[64 + lane] : 0;
    const float bg_lo  = s_bgs[lane];
    const float bg_hi  = hi_ok ? s_bgs[64 + lane] : 0.f;

    const float ratio    = pi ? rd[0]   : ru[0];    // wave-uniform -> SGPR
    const float slack_pr = pi ? vosp[0] : voll[0];

    const float om  = omega[(size_t)b * T_ + t];    // coalesced 192-lane runs
    const float dem = pi ? fmaxf(-om, 0.f) : fmaxf(om, 0.f);
    const float* __restrict__ capp = (pi ? R_dn : R_up) + (size_t)b * TILE + t;
    float* __restrict__ gcol = out + (size_t)pi * bgt + (size_t)b * TILE + t;

    // ---- scan: 32 ranks unconditional in one flight (typical wave-max k*
    // ~28-34), ballot-gated 16s for the tail; write-once everywhere ----
    float before = 0.f, objp = 0.f;
    scan_chunk<32>( 0, capp, gcol, ord_lo, ord_hi, bg_lo, bg_hi, ratio, dem, before, objp);
    int K = 32;
    bool run = __any(before < dem);
    if (run) { scan_chunk<16>(32, capp, gcol, ord_lo, ord_hi, bg_lo, bg_hi, ratio, dem, before, objp);
               K = 48; run = __any(before < dem); }
    if (run) { scan_chunk<16>(48, capp, gcol, ord_lo, ord_hi, bg_lo, bg_hi, ratio, dem, before, objp);
               K = 64; run = __any(before < dem); }
    if (run) { scan_chunk<16>(64, capp, gcol, ord_lo, ord_hi, bg_lo, bg_hi, ratio, dem, before, objp);
               K = 80; run = __any(before < dem); }
    if (run) { scan_chunk<16>(80, capp, gcol, ord_lo, ord_hi, bg_lo, bg_hi, ratio, dem, before, objp);
               K = 96; run = __any(before < dem); }
    if (run) { scan_chunk< 4>(96, capp, gcol, ord_lo, ord_hi, bg_lo, bg_hi, ratio, dem, before, objp);
               K = 100; }

    // tail-zero: rows ord[K..99] never executed -> write their zeros (K is
    // wave-uniform; readlane with uniform runtime index). Write-once holds.
    for (int r = K; r < G_; ++r) {
        const int g = (r < 64) ? __builtin_amdgcn_readlane(ord_lo, r)
                               : __builtin_amdgcn_readlane(ord_hi, r - 64);
        gcol[g * T_] = 0.f;
    }

    // slack (rank 100): clip(dem - before, 0, dem); early exit -> 0 exactly.
    const float slackv = fmaxf(dem - before, 0.f);
    objp = fmaf(slack_pr, slackv, objp);
    out[2 * bgt + (size_t)pi * B * T_ + (size_t)b * T_ + t] = slackv;

    // ---- rt_obj: per-column partials -> LDS; pair up+dn; sum 24 t's ----
    s_oc[tid] = objp;
    __syncthreads();
    if (tid < BPB * T_) s_oc[tid] += s_oc[tid + BPB * T_];   // up + dn
    __syncthreads();
    if (tid < BPB) {
        float s = 0.f;
#pragma unroll
        for (int j = 0; j < T_; ++j) s += s_oc[tid * T_ + j];
        out[2 * bgt + 2 * (size_t)B * T_ + (size_t)blockIdx.x * BPB + tid] = s;
    }
}

extern "C" void kernel_launch(void* const* d_in, const int* in_sizes, int n_in,
                              void* d_out, int out_size, void* d_ws, size_t ws_size,
                              hipStream_t stream)
{
    const float* R_up  = (const float*)d_in[0];
    const float* R_dn  = (const float*)d_in[1];
    const float* omega = (const float*)d_in[2];
    const float* b_G   = (const float*)d_in[3];
    const float* voll  = (const float*)d_in[4];
    const float* vosp  = (const float*)d_in[5];
    const float* ru    = (const float*)d_in[6];
    const float* rd    = (const float*)d_in[7];

    const int B = in_sizes[0] / TILE;
    float* out = (float*)d_out;

    // one thread per (b,pass,t) column: 384 threads = 8 b's x 2 passes x 24 t
    dispatch_kernel<<<B / BPB, BLOCK, 0, stream>>>(
        R_up, R_dn, omega, b_G, voll, vosp, ru, rd, out, B);
}

// Round 7
// 156.155 us; speedup vs baseline: 1.0516x; 1.0516x over previous
//
#include <hip/hip_runtime.h>

#define G_ 100
#define T_ 24
#define GP1 101
#define TILE (G_ * T_)        // 2400 floats per (b,pass) tile
#define VPB (TILE / 4)        // 600 float4 per tile
#define BPB 4                 // b's per block
#define WPB (BPB * 2)         // 8 waves: 4 b's x 2 passes
#define BLOCK (64 * WPB)      // 512 threads

typedef float vfloat4 __attribute__((ext_vector_type(4)));

// ---------------- kernel 1: streaming zero-fill of the du/dd region -------
// Same access pattern as the 6.6 TB/s harness fill: 1KB/inst coalesced f4.
__global__ __launch_bounds__(256, 8) void zero_fill(vfloat4* __restrict__ p,
                                                    long n4)
{
    long i      = (long)blockIdx.x * blockDim.x + threadIdx.x;
    long stride = (long)gridDim.x * blockDim.x;
    for (; i < n4; i += stride) p[i] = (vfloat4)(0.f);
}

// ---------------- kernel 2: merit-order scan (R2 structure) ---------------
// Gated chunk: N 96B-row cap loads, serial clip-scan, allocs stored
// directly to the (pre-zeroed) global output rows. Only executed rows are
// ever written here; untouched rows keep the fill kernel's zeros.
// ord/price come from per-wave registers via v_readlane (uniform -> SGPR,
// exec-mask-ignoring, safe under the lane<24 divergent branch).
template<int N>
__device__ __forceinline__ void scan_chunk(int k0,
    const float* __restrict__ capp,          // R_p[b] + t (per-lane)
    float* __restrict__ gcol,                // out tile + t (per-lane)
    int ord_lo, int ord_hi, float pr_lo, float pr_hi,
    float dem, float& before, float& objp)
{
    int gg[N]; float pr[N], cap[N];
#pragma unroll
    for (int j = 0; j < N; ++j) {
        const int idx = k0 + j;              // compile-time constant
        if (idx < 64) {
            gg[j] = __builtin_amdgcn_readlane(ord_lo, idx);
            pr[j] = __int_as_float(__builtin_amdgcn_readlane(__float_as_int(pr_lo), idx));
        } else {
            gg[j] = __builtin_amdgcn_readlane(ord_hi, idx - 64);
            pr[j] = __int_as_float(__builtin_amdgcn_readlane(__float_as_int(pr_hi), idx - 64));
        }
    }
#pragma unroll
    for (int j = 0; j < N; ++j) cap[j] = capp[gg[j] * T_];
#pragma unroll
    for (int j = 0; j < N; ++j) {
        float a = fminf(fmaxf(dem - before, 0.f), cap[j]);
        before += cap[j];
        objp = fmaf(pr[j], a, objp);
        gcol[gg[j] * T_] = a;                // overwrite pre-zeroed row
    }
}

__global__ __launch_bounds__(BLOCK, 8) void dispatch_kernel(
    const float* __restrict__ R_up, const float* __restrict__ R_dn,
    const float* __restrict__ omega,
    const float* __restrict__ b_G, const float* __restrict__ voll,
    const float* __restrict__ vosp, const float* __restrict__ ru,
    const float* __restrict__ rd,
    float* __restrict__ out, int B)
{
    // tiny LDS only -> occupancy is wave-limited
    __shared__ float s_praw[2][GP1];
    __shared__ int   s_ord [2][128];
    __shared__ float s_pr  [2][128];
    __shared__ float s_obj [WPB];

    const int tid  = threadIdx.x;
    const int w    = tid >> 6;
    const int lane = tid & 63;
    const int b = __builtin_amdgcn_readfirstlane(blockIdx.x * BPB + (w >> 1));
    const int p = __builtin_amdgcn_readfirstlane(w & 1);
    const size_t bgt = (size_t)B * TILE;

    // omega issued FIRST: its HBM round drains under the sort
    float om = 0.f;
    if (lane < T_) om = omega[(size_t)b * T_ + lane];

    // ---- fused merit-order sort (== stable jnp.argsort of prices) ----
    {   // up-ranks on threads [0,101), dn-ranks on threads [256,357)
        const int sp = tid >> 8;
        const int si = tid & 255;
        if (si < GP1) {
            float m;
            if (si < G_) m = (sp ? rd[0] : ru[0]) * b_G[si];
            else         m = sp ? vosp[0] : voll[0];
            s_praw[sp][si] = m;
        }
        __syncthreads();
        if (si < GP1) {
            const float m = s_praw[sp][si];
            int r = 0;
            // fully unrolled: 101 independent contiguous ds_reads pipeline
            // (b128-batchable) instead of a serial latency-bound loop
#pragma unroll
            for (int j = 0; j < GP1; ++j) {
                const float v = s_praw[sp][j];
                r += (v < m) || (v == m && j < si);
            }
            s_ord[sp][r] = si;  s_pr[sp][r] = m;
        }
    }
    __syncthreads();

    // ---- cache this wave's sorted merit order in registers ----
    const int hi_ok = (lane < GP1 - 64);
    const int   ord_lo = s_ord[p][lane];
    const int   ord_hi = hi_ok ? s_ord[p][64 + lane] : 0;
    const float pr_lo  = s_pr [p][lane];
    const float pr_hi  = hi_ok ? s_pr [p][64 + lane] : 0.f;

    // ---- gated scan (R2 ladder): writes ONLY executed rows ----
    const int t = (lane < T_) ? lane : 0;
    float objp = 0.f;
    if (lane < T_) {
        const float dem = p ? fmaxf(-om, 0.f) : fmaxf(om, 0.f);
        const float* __restrict__ capp = (p ? R_dn : R_up) + (size_t)b * TILE + t;
        float* __restrict__ gcol = out + (size_t)p * bgt + (size_t)b * TILE + t;

        float before = 0.f;
        scan_chunk<16>( 0, capp, gcol, ord_lo, ord_hi, pr_lo, pr_hi, dem, before, objp);
        bool run = __any(before < dem);
        if (run) { scan_chunk<16>(16, capp, gcol, ord_lo, ord_hi, pr_lo, pr_hi, dem, before, objp);
                   run = __any(before < dem); }
        if (run) { scan_chunk< 8>(32, capp, gcol, ord_lo, ord_hi, pr_lo, pr_hi, dem, before, objp);
                   run = __any(before < dem); }
        if (run) { scan_chunk< 8>(40, capp, gcol, ord_lo, ord_hi, pr_lo, pr_hi, dem, before, objp);
                   run = __any(before < dem); }
        if (run) { scan_chunk< 8>(48, capp, gcol, ord_lo, ord_hi, pr_lo, pr_hi, dem, before, objp);
                   run = __any(before < dem); }
        if (run) { scan_chunk< 8>(56, capp, gcol, ord_lo, ord_hi, pr_lo, pr_hi, dem, before, objp);
                   run = __any(before < dem); }
        if (run) { scan_chunk< 8>(64, capp, gcol, ord_lo, ord_hi, pr_lo, pr_hi, dem, before, objp);
                   run = __any(before < dem); }
        if (run) { scan_chunk< 8>(72, capp, gcol, ord_lo, ord_hi, pr_lo, pr_hi, dem, before, objp);
                   run = __any(before < dem); }
        if (run) { scan_chunk< 8>(80, capp, gcol, ord_lo, ord_hi, pr_lo, pr_hi, dem, before, objp);
                   run = __any(before < dem); }
        if (run) { scan_chunk< 8>(88, capp, gcol, ord_lo, ord_hi, pr_lo, pr_hi, dem, before, objp);
                   run = __any(before < dem); }
        if (run)   scan_chunk< 4>(96, capp, gcol, ord_lo, ord_hi, pr_lo, pr_hi, dem, before, objp);

        // slack (rank 100 == GP1-1): clip(dem - before, 0, dem)
        const float slack_pr =
            __int_as_float(__builtin_amdgcn_readlane(__float_as_int(pr_hi), GP1 - 1 - 64));
        const float slackv = fmaxf(dem - before, 0.f);
        objp = fmaf(slack_pr, slackv, objp);
        out[2 * bgt + (size_t)p * B * T_ + (size_t)b * T_ + t] = slackv;
    }

    // ---- rt_obj partial: butterfly over the wave (idle lanes hold 0) ----
#pragma unroll
    for (int off = 32; off; off >>= 1) objp += __shfl_xor(objp, off, 64);
    if (lane == 0) s_obj[w] = objp;

    // ---- pair up+dn partials per b ----
    __syncthreads();
    if ((tid & 127) == 0)
        out[2 * bgt + 2 * (size_t)B * T_ + b] = s_obj[w] + s_obj[w + 1];
}

extern "C" void kernel_launch(void* const* d_in, const int* in_sizes, int n_in,
                              void* d_out, int out_size, void* d_ws, size_t ws_size,
                              hipStream_t stream)
{
    const float* R_up  = (const float*)d_in[0];
    const float* R_dn  = (const float*)d_in[1];
    const float* omega = (const float*)d_in[2];
    const float* b_G   = (const float*)d_in[3];
    const float* voll  = (const float*)d_in[4];
    const float* vosp  = (const float*)d_in[5];
    const float* ru    = (const float*)d_in[6];
    const float* rd    = (const float*)d_in[7];

    const int B = in_sizes[0] / TILE;
    float* out = (float*)d_out;

    // 1. zero du/dd region at streaming BW (write-pattern == harness fill)
    const long n4 = (long)2 * B * TILE / 4;
    zero_fill<<<2048, 256, 0, stream>>>((vfloat4*)out, n4);

    // 2. scatter-only scan: 8 waves/block = 4 b's x 2 passes; grid B/4
    dispatch_kernel<<<B / BPB, BLOCK, 0, stream>>>(
        R_up, R_dn, omega, b_G, voll, vosp, ru, rd, out, B);
}